// Round 2
// baseline (1041.169 us; speedup 1.0000x reference)
//
#include <hip/hip_runtime.h>

#define NN 50000
#define NE 1600000
#define NG 512
#define IN_DIM 128
#define HID 64

// deg[dst] += edge_attr[e]  (self-loop weight 1 added later in dis_kernel)
__global__ void deg_kernel(const int* __restrict__ ei,
                           const float* __restrict__ ea,
                           float* __restrict__ deg) {
    int e = blockIdx.x * blockDim.x + threadIdx.x;
    if (e < NE) {
        int dst = ei[NE + e];
        atomicAdd(&deg[dst], ea[e]);
    }
}

// in-place: deg -> dis = rsqrt(deg + 1)
__global__ void dis_kernel(float* __restrict__ deg) {
    int i = blockIdx.x * blockDim.x + threadIdx.x;
    if (i < NN) deg[i] = rsqrtf(deg[i] + 1.0f);
}

// Y[n,HID] = X[n,K] @ W[K,HID].  W staged in LDS. 1 wave per row, lane = col.
template <int K>
__global__ void gemm_kernel(const float* __restrict__ X,
                            const float* __restrict__ W,
                            float* __restrict__ Y) {
    __shared__ float w_lds[K * HID];
    for (int idx = threadIdx.x; idx < K * HID; idx += blockDim.x)
        w_lds[idx] = W[idx];
    __syncthreads();
    int wave = threadIdx.x >> 6;
    int lane = threadIdx.x & 63;
    int row = blockIdx.x * 4 + wave;
    if (row >= NN) return;
    const float4* x4 = (const float4*)(X + (size_t)row * K);
    float acc = 0.0f;
#pragma unroll
    for (int k4 = 0; k4 < K / 4; ++k4) {
        float4 xv = x4[k4];
        acc += xv.x * w_lds[(k4 * 4 + 0) * HID + lane];
        acc += xv.y * w_lds[(k4 * 4 + 1) * HID + lane];
        acc += xv.z * w_lds[(k4 * 4 + 2) * HID + lane];
        acc += xv.w * w_lds[(k4 * 4 + 3) * HID + lane];
    }
    Y[(size_t)row * HID + lane] = acc;
}

// AGG[dst, lane] += dis[src]*ea[e]*dis[dst] * HW[src, lane]   (1 wave / edge)
__global__ void edge_agg_kernel(const int* __restrict__ ei,
                                const float* __restrict__ ea,
                                const float* __restrict__ dis,
                                const float* __restrict__ HW,
                                float* __restrict__ AGG) {
    int e = blockIdx.x * 4 + (threadIdx.x >> 6);
    int lane = threadIdx.x & 63;
    if (e >= NE) return;
    int src = ei[e];
    int dst = ei[NE + e];
    float nrm = dis[src] * ea[e] * dis[dst];
    float v = nrm * HW[(size_t)src * HID + lane];
    atomicAdd(&AGG[(size_t)dst * HID + lane], v);
}

// B = relu(B + dis^2 * A + b1)   (self-loop + bias + relu, in place)
__global__ void epi1_kernel(float* __restrict__ B, const float* __restrict__ A,
                            const float* __restrict__ dis,
                            const float* __restrict__ b1) {
    int i = blockIdx.x * blockDim.x + threadIdx.x;
    if (i >= NN * HID) return;
    int node = i >> 6;
    int c = i & 63;
    float d = dis[node];
    float v = B[i] + d * d * A[i] + b1[c];
    B[i] = fmaxf(v, 0.0f);
}

// h2 = B + dis^2*A + b2 ; pooled[batch] += h2 ; cnt[batch] += 1
__global__ void pool_kernel(const float* __restrict__ B,
                            const float* __restrict__ A,
                            const float* __restrict__ dis,
                            const float* __restrict__ b2,
                            const int* __restrict__ batch,
                            float* __restrict__ pooled,
                            float* __restrict__ cnt) {
    int i = blockIdx.x * blockDim.x + threadIdx.x;
    if (i >= NN * HID) return;
    int node = i >> 6;
    int c = i & 63;
    float d = dis[node];
    float v = B[i] + d * d * A[i] + b2[c];
    int g = batch[node];
    atomicAdd(&pooled[g * HID + c], v);
    if (c == 0) atomicAdd(&cnt[g], 1.0f);
}

// out[g] = (pooled[g]/max(cnt,1)) . Wlin + blin   (1 block of 64 per graph)
__global__ void out_kernel(const float* __restrict__ pooled,
                           const float* __restrict__ cnt,
                           const float* __restrict__ Wlin,
                           const float* __restrict__ blin,
                           float* __restrict__ out) {
    int g = blockIdx.x;
    int lane = threadIdx.x;
    float cc = fmaxf(cnt[g], 1.0f);
    float v = pooled[g * HID + lane] / cc * Wlin[lane];
    for (int off = 32; off > 0; off >>= 1) v += __shfl_down(v, off, 64);
    if (lane == 0) out[g] = v + blin[0];
}

extern "C" void kernel_launch(void* const* d_in, const int* in_sizes, int n_in,
                              void* d_out, int out_size, void* d_ws, size_t ws_size,
                              hipStream_t stream) {
    const float* x     = (const float*)d_in[0];
    const int*   ei    = (const int*)d_in[1];
    const float* ea    = (const float*)d_in[2];
    const int*   batch = (const int*)d_in[3];
    const float* W1    = (const float*)d_in[4];
    const float* b1    = (const float*)d_in[5];
    const float* W2    = (const float*)d_in[6];
    const float* b2    = (const float*)d_in[7];
    const float* Wlin  = (const float*)d_in[8];
    const float* blin  = (const float*)d_in[9];
    float*       out   = (float*)d_out;

    char* ws = (char*)d_ws;
    auto alloc = [&](size_t bytes) {
        void* p = (void*)ws;
        ws += (bytes + 255) / 256 * 256;
        return p;
    };
    float* dis    = (float*)alloc((size_t)NN * 4);
    float* A      = (float*)alloc((size_t)NN * HID * 4);   // hw1 then hw2
    float* B      = (float*)alloc((size_t)NN * HID * 4);   // agg1/h1 then agg2
    float* pooled = (float*)alloc((size_t)NG * HID * 4);
    float* cnt    = (float*)alloc((size_t)NG * 4);

    // degree -> dis
    hipMemsetAsync(dis, 0, (size_t)NN * 4, stream);
    deg_kernel<<<(NE + 255) / 256, 256, 0, stream>>>(ei, ea, dis);
    dis_kernel<<<(NN + 255) / 256, 256, 0, stream>>>(dis);

    // conv1
    gemm_kernel<IN_DIM><<<(NN + 3) / 4, 256, 0, stream>>>(x, W1, A);
    hipMemsetAsync(B, 0, (size_t)NN * HID * 4, stream);
    edge_agg_kernel<<<(NE + 3) / 4, 256, 0, stream>>>(ei, ea, dis, A, B);
    epi1_kernel<<<(NN * HID + 255) / 256, 256, 0, stream>>>(B, A, dis, b1);

    // conv2
    gemm_kernel<HID><<<(NN + 3) / 4, 256, 0, stream>>>(B, W2, A);
    hipMemsetAsync(B, 0, (size_t)NN * HID * 4, stream);
    edge_agg_kernel<<<(NE + 3) / 4, 256, 0, stream>>>(ei, ea, dis, A, B);

    // pool + head
    hipMemsetAsync(pooled, 0, (size_t)NG * HID * 4, stream);
    hipMemsetAsync(cnt, 0, (size_t)NG * 4, stream);
    pool_kernel<<<(NN * HID + 255) / 256, 256, 0, stream>>>(B, A, dis, b2, batch,
                                                            pooled, cnt);
    out_kernel<<<NG, 64, 0, stream>>>(pooled, cnt, Wlin, blin, out);
}

// Round 3
// 547.382 us; speedup vs baseline: 1.9021x; 1.9021x over previous
//
#include <hip/hip_runtime.h>

#define NN 50000
#define NE 1600000
#define NG 512
#define IN_DIM 128
#define HID 64
#define CHUNK 512
#define NCH ((NN + CHUNK - 1) / CHUNK)   // 98

// deg[dst] += ea[e]; indeg[dst] += 1
__global__ void deg_cnt_kernel(const int* __restrict__ ei,
                               const float* __restrict__ ea,
                               float* __restrict__ deg,
                               int* __restrict__ indeg) {
    int e = blockIdx.x * blockDim.x + threadIdx.x;
    if (e < NE) {
        int dst = ei[NE + e];
        atomicAdd(&deg[dst], ea[e]);
        atomicAdd(&indeg[dst], 1);
    }
}

// in-place: deg -> dis = rsqrt(deg + 1)   (self-loop weight 1)
__global__ void dis_kernel(float* __restrict__ deg) {
    int i = blockIdx.x * blockDim.x + threadIdx.x;
    if (i < NN) deg[i] = rsqrtf(deg[i] + 1.0f);
}

// ---- 3-phase exclusive scan of indeg -> offs (and cursor copy) ----
__global__ void chunksum_kernel(const int* __restrict__ cnt, int* __restrict__ csum) {
    __shared__ int s[256];
    int b = blockIdx.x, t = threadIdx.x;
    int base = b * CHUNK;
    int v = 0;
    for (int i = t; i < CHUNK; i += 256) {
        int idx = base + i;
        if (idx < NN) v += cnt[idx];
    }
    s[t] = v;
    __syncthreads();
    for (int off = 128; off > 0; off >>= 1) {
        if (t < off) s[t] += s[t + off];
        __syncthreads();
    }
    if (t == 0) csum[b] = s[0];
}

__global__ void scanchunks_kernel(const int* __restrict__ csum, int* __restrict__ coff) {
    __shared__ int s[128];
    int t = threadIdx.x;
    int v = (t < NCH) ? csum[t] : 0;
    s[t] = v;
    __syncthreads();
    for (int off = 1; off < 128; off <<= 1) {
        int add = (t >= off) ? s[t - off] : 0;
        __syncthreads();
        s[t] += add;
        __syncthreads();
    }
    if (t < NCH) coff[t] = s[t] - v;   // exclusive
}

__global__ void chunkscan_kernel(const int* __restrict__ cnt,
                                 const int* __restrict__ coff,
                                 int* __restrict__ offs,
                                 int* __restrict__ cursor) {
    __shared__ int s[CHUNK];
    int b = blockIdx.x, t = threadIdx.x;
    int idx = b * CHUNK + t;
    int v = (idx < NN) ? cnt[idx] : 0;
    s[t] = v;
    __syncthreads();
    for (int off = 1; off < CHUNK; off <<= 1) {
        int add = (t >= off) ? s[t - off] : 0;
        __syncthreads();
        s[t] += add;
        __syncthreads();
    }
    if (idx < NN) {
        int ex = coff[b] + s[t] - v;
        offs[idx] = ex;
        cursor[idx] = ex;
    }
}

// csr[pos] = {src, norm} grouped by dst
__global__ void fill_kernel(const int* __restrict__ ei, const float* __restrict__ ea,
                            const float* __restrict__ dis,
                            int* __restrict__ cursor, int2* __restrict__ csr) {
    int e = blockIdx.x * blockDim.x + threadIdx.x;
    if (e >= NE) return;
    int src = ei[e];
    int dst = ei[NE + e];
    float w = dis[src] * ea[e] * dis[dst];
    int pos = atomicAdd(&cursor[dst], 1);
    csr[pos] = make_int2(src, __float_as_int(w));
}

// Y[n,HID] = X[n,K] @ W[K,HID].  W staged in LDS. 1 wave per row, lane = col.
template <int K>
__global__ void gemm_kernel(const float* __restrict__ X,
                            const float* __restrict__ W,
                            float* __restrict__ Y) {
    __shared__ float w_lds[K * HID];
    for (int idx = threadIdx.x; idx < K * HID; idx += blockDim.x)
        w_lds[idx] = W[idx];
    __syncthreads();
    int wave = threadIdx.x >> 6;
    int lane = threadIdx.x & 63;
    int row = blockIdx.x * 4 + wave;
    if (row >= NN) return;
    const float4* x4 = (const float4*)(X + (size_t)row * K);
    float acc = 0.0f;
#pragma unroll
    for (int k4 = 0; k4 < K / 4; ++k4) {
        float4 xv = x4[k4];
        acc += xv.x * w_lds[(k4 * 4 + 0) * HID + lane];
        acc += xv.y * w_lds[(k4 * 4 + 1) * HID + lane];
        acc += xv.z * w_lds[(k4 * 4 + 2) * HID + lane];
        acc += xv.w * w_lds[(k4 * 4 + 3) * HID + lane];
    }
    Y[(size_t)row * HID + lane] = acc;
}

// OUT[node] = relu( sum_e w*HW[src] + dis^2*HW[node] + bias )   (1 wave/node)
__global__ void gather_relu_kernel(const int2* __restrict__ csr,
                                   const int* __restrict__ offs,
                                   const int* __restrict__ indeg,
                                   const float* __restrict__ dis,
                                   const float* __restrict__ HW,
                                   const float* __restrict__ bias,
                                   float* __restrict__ OUT) {
    int node = blockIdx.x * 4 + (threadIdx.x >> 6);
    int lane = threadIdx.x & 63;
    if (node >= NN) return;
    int start = offs[node];
    int n = indeg[node];
    float d = dis[node];
    float a0 = d * d * HW[(size_t)node * HID + lane];
    float a1 = 0.f, a2 = 0.f, a3 = 0.f;
    int j = 0;
    for (; j + 4 <= n; j += 4) {
        int2 r0 = csr[start + j + 0];
        int2 r1 = csr[start + j + 1];
        int2 r2 = csr[start + j + 2];
        int2 r3 = csr[start + j + 3];
        a0 += __int_as_float(r0.y) * HW[(size_t)r0.x * HID + lane];
        a1 += __int_as_float(r1.y) * HW[(size_t)r1.x * HID + lane];
        a2 += __int_as_float(r2.y) * HW[(size_t)r2.x * HID + lane];
        a3 += __int_as_float(r3.y) * HW[(size_t)r3.x * HID + lane];
    }
    for (; j < n; ++j) {
        int2 r = csr[start + j];
        a0 += __int_as_float(r.y) * HW[(size_t)r.x * HID + lane];
    }
    float v = (a0 + a1) + (a2 + a3) + bias[lane];
    OUT[(size_t)node * HID + lane] = fmaxf(v, 0.0f);
}

// layer-2 gather fused with mean-pool accumulation
__global__ void gather_pool_kernel(const int2* __restrict__ csr,
                                   const int* __restrict__ offs,
                                   const int* __restrict__ indeg,
                                   const float* __restrict__ dis,
                                   const float* __restrict__ HW,
                                   const float* __restrict__ bias,
                                   const int* __restrict__ batch,
                                   float* __restrict__ pooled) {
    int node = blockIdx.x * 4 + (threadIdx.x >> 6);
    int lane = threadIdx.x & 63;
    if (node >= NN) return;
    int start = offs[node];
    int n = indeg[node];
    float d = dis[node];
    float a0 = d * d * HW[(size_t)node * HID + lane];
    float a1 = 0.f, a2 = 0.f, a3 = 0.f;
    int j = 0;
    for (; j + 4 <= n; j += 4) {
        int2 r0 = csr[start + j + 0];
        int2 r1 = csr[start + j + 1];
        int2 r2 = csr[start + j + 2];
        int2 r3 = csr[start + j + 3];
        a0 += __int_as_float(r0.y) * HW[(size_t)r0.x * HID + lane];
        a1 += __int_as_float(r1.y) * HW[(size_t)r1.x * HID + lane];
        a2 += __int_as_float(r2.y) * HW[(size_t)r2.x * HID + lane];
        a3 += __int_as_float(r3.y) * HW[(size_t)r3.x * HID + lane];
    }
    for (; j < n; ++j) {
        int2 r = csr[start + j];
        a0 += __int_as_float(r.y) * HW[(size_t)r.x * HID + lane];
    }
    float v = (a0 + a1) + (a2 + a3) + bias[lane];
    atomicAdd(&pooled[batch[node] * HID + lane], v);
}

// gcnt[batch[i]] += 1
__global__ void gcnt_kernel(const int* __restrict__ batch, float* __restrict__ gcnt) {
    int i = blockIdx.x * blockDim.x + threadIdx.x;
    if (i < NN) atomicAdd(&gcnt[batch[i]], 1.0f);
}

// out[g] = (pooled[g]/max(cnt,1)) . Wlin + blin
__global__ void out_kernel(const float* __restrict__ pooled,
                           const float* __restrict__ gcnt,
                           const float* __restrict__ Wlin,
                           const float* __restrict__ blin,
                           float* __restrict__ out) {
    int g = blockIdx.x;
    int lane = threadIdx.x;
    float cc = fmaxf(gcnt[g], 1.0f);
    float v = pooled[g * HID + lane] / cc * Wlin[lane];
    for (int off = 32; off > 0; off >>= 1) v += __shfl_down(v, off, 64);
    if (lane == 0) out[g] = v + blin[0];
}

extern "C" void kernel_launch(void* const* d_in, const int* in_sizes, int n_in,
                              void* d_out, int out_size, void* d_ws, size_t ws_size,
                              hipStream_t stream) {
    const float* x     = (const float*)d_in[0];
    const int*   ei    = (const int*)d_in[1];
    const float* ea    = (const float*)d_in[2];
    const int*   batch = (const int*)d_in[3];
    const float* W1    = (const float*)d_in[4];
    const float* b1    = (const float*)d_in[5];
    const float* W2    = (const float*)d_in[6];
    const float* b2    = (const float*)d_in[7];
    const float* Wlin  = (const float*)d_in[8];
    const float* blin  = (const float*)d_in[9];
    float*       out   = (float*)d_out;

    char* ws = (char*)d_ws;
    auto alloc = [&](size_t bytes) {
        void* p = (void*)ws;
        ws += (bytes + 255) / 256 * 256;
        return p;
    };
    float* dis    = (float*)alloc((size_t)NN * 4);
    int*   indeg  = (int*)alloc((size_t)NN * 4);
    int*   offs   = (int*)alloc((size_t)NN * 4);
    int*   cursor = (int*)alloc((size_t)NN * 4);
    int*   csum   = (int*)alloc((size_t)NCH * 4);
    int*   coff   = (int*)alloc((size_t)NCH * 4);
    int2*  csr    = (int2*)alloc((size_t)NE * 8);
    float* A      = (float*)alloc((size_t)NN * HID * 4);   // hw1 then hw2
    float* B      = (float*)alloc((size_t)NN * HID * 4);   // h1
    float* pooled = (float*)alloc((size_t)NG * HID * 4);
    float* gcnt   = (float*)alloc((size_t)NG * 4);

    // degree + in-degree -> dis
    hipMemsetAsync(dis, 0, (size_t)NN * 4, stream);
    hipMemsetAsync(indeg, 0, (size_t)NN * 4, stream);
    deg_cnt_kernel<<<(NE + 255) / 256, 256, 0, stream>>>(ei, ea, dis, indeg);
    dis_kernel<<<(NN + 255) / 256, 256, 0, stream>>>(dis);

    // CSR build
    chunksum_kernel<<<NCH, 256, 0, stream>>>(indeg, csum);
    scanchunks_kernel<<<1, 128, 0, stream>>>(csum, coff);
    chunkscan_kernel<<<NCH, CHUNK, 0, stream>>>(indeg, coff, offs, cursor);
    fill_kernel<<<(NE + 255) / 256, 256, 0, stream>>>(ei, ea, dis, cursor, csr);

    // conv1: h1 = relu(gather(x@W1) + self + b1)
    gemm_kernel<IN_DIM><<<(NN + 3) / 4, 256, 0, stream>>>(x, W1, A);
    gather_relu_kernel<<<(NN + 3) / 4, 256, 0, stream>>>(csr, offs, indeg, dis, A, b1, B);

    // conv2 fused with pool
    gemm_kernel<HID><<<(NN + 3) / 4, 256, 0, stream>>>(B, W2, A);
    hipMemsetAsync(pooled, 0, (size_t)NG * HID * 4, stream);
    hipMemsetAsync(gcnt, 0, (size_t)NG * 4, stream);
    gcnt_kernel<<<(NN + 255) / 256, 256, 0, stream>>>(batch, gcnt);
    gather_pool_kernel<<<(NN + 3) / 4, 256, 0, stream>>>(csr, offs, indeg, dis, A, b2,
                                                         batch, pooled);

    // head
    out_kernel<<<NG, 64, 0, stream>>>(pooled, gcnt, Wlin, blin, out);
}

// Round 4
// 537.687 us; speedup vs baseline: 1.9364x; 1.0180x over previous
//
#include <hip/hip_runtime.h>

#define NN 50000
#define NE 1600000
#define NG 512
#define IN_DIM 128
#define HID 64
#define CHUNK 512
#define NCH ((NN + CHUNK - 1) / CHUNK)   // 98

#define RR 8                 // node ranges
#define CC 32                // edge chunks
#define BINS (NN / RR)       // 6250 bins per range
#define EC (NE / CC)         // 50000 edges per chunk

// ---- histogram: per-(range,chunk) LDS count + weighted-degree sum ----
__global__ void hist_kernel(const int* __restrict__ ei, const float* __restrict__ ea,
                            int* __restrict__ pc, float* __restrict__ ps) {
    __shared__ int cnt[BINS];
    __shared__ float sum[BINS];
    int r = blockIdx.x / CC;
    int c = blockIdx.x % CC;
    for (int i = threadIdx.x; i < BINS; i += blockDim.x) { cnt[i] = 0; sum[i] = 0.f; }
    __syncthreads();
    int base = c * EC;
    int lo = r * BINS;
    for (int e = base + threadIdx.x; e < base + EC; e += blockDim.x) {
        int dst = ei[NE + e];
        unsigned bin = (unsigned)(dst - lo);
        if (bin < BINS) {
            atomicAdd(&cnt[bin], 1);
            atomicAdd(&sum[bin], ea[e]);
        }
    }
    __syncthreads();
    int*   pcc = pc + (size_t)c * NN + lo;
    float* psc = ps + (size_t)c * NN + lo;
    for (int i = threadIdx.x; i < BINS; i += blockDim.x) { pcc[i] = cnt[i]; psc[i] = sum[i]; }
}

// indeg[n] = sum_c pc[c][n] ; dis[n] = rsqrt(1 + sum_c ps[c][n])
__global__ void reduce_kernel(const int* __restrict__ pc, const float* __restrict__ ps,
                              int* __restrict__ indeg, float* __restrict__ dis) {
    int n = blockIdx.x * blockDim.x + threadIdx.x;
    if (n >= NN) return;
    int ci = 0; float s = 0.f;
    for (int c = 0; c < CC; ++c) {
        ci += pc[(size_t)c * NN + n];
        s  += ps[(size_t)c * NN + n];
    }
    indeg[n] = ci;
    dis[n] = rsqrtf(s + 1.0f);
}

// ---- 3-phase exclusive scan of indeg -> offs ----
__global__ void chunksum_kernel(const int* __restrict__ cnt, int* __restrict__ csum) {
    __shared__ int s[256];
    int b = blockIdx.x, t = threadIdx.x;
    int base = b * CHUNK;
    int v = 0;
    for (int i = t; i < CHUNK; i += 256) {
        int idx = base + i;
        if (idx < NN) v += cnt[idx];
    }
    s[t] = v;
    __syncthreads();
    for (int off = 128; off > 0; off >>= 1) {
        if (t < off) s[t] += s[t + off];
        __syncthreads();
    }
    if (t == 0) csum[b] = s[0];
}

__global__ void scanchunks_kernel(const int* __restrict__ csum, int* __restrict__ coff) {
    __shared__ int s[128];
    int t = threadIdx.x;
    int v = (t < NCH) ? csum[t] : 0;
    s[t] = v;
    __syncthreads();
    for (int off = 1; off < 128; off <<= 1) {
        int add = (t >= off) ? s[t - off] : 0;
        __syncthreads();
        s[t] += add;
        __syncthreads();
    }
    if (t < NCH) coff[t] = s[t] - v;   // exclusive
}

__global__ void chunkscan_kernel(const int* __restrict__ cnt,
                                 const int* __restrict__ coff,
                                 int* __restrict__ offs) {
    __shared__ int s[CHUNK];
    int b = blockIdx.x, t = threadIdx.x;
    int idx = b * CHUNK + t;
    int v = (idx < NN) ? cnt[idx] : 0;
    s[t] = v;
    __syncthreads();
    for (int off = 1; off < CHUNK; off <<= 1) {
        int add = (t >= off) ? s[t - off] : 0;
        __syncthreads();
        s[t] += add;
        __syncthreads();
    }
    if (idx < NN) offs[idx] = coff[b] + s[t] - v;
}

// in-place pc[c][n] -> chunk base offset (exclusive scan over c, seeded by offs)
__global__ void chunkoff_kernel(int* __restrict__ pc, const int* __restrict__ offs) {
    int n = blockIdx.x * blockDim.x + threadIdx.x;
    if (n >= NN) return;
    int run = offs[n];
    for (int c = 0; c < CC; ++c) {
        size_t idx = (size_t)c * NN + n;
        int t = pc[idx];
        pc[idx] = run;
        run += t;
    }
}

// csr[pos] = {src, norm} grouped by dst; positions from chunkoff + LDS cursor
__global__ void fill_kernel(const int* __restrict__ ei, const float* __restrict__ ea,
                            const float* __restrict__ dis,
                            const int* __restrict__ pc, int2* __restrict__ csr) {
    __shared__ int cur[BINS];
    int r = blockIdx.x / CC;
    int c = blockIdx.x % CC;
    for (int i = threadIdx.x; i < BINS; i += blockDim.x) cur[i] = 0;
    __syncthreads();
    int base = c * EC;
    int lo = r * BINS;
    const int* pcb = pc + (size_t)c * NN;
    for (int e = base + threadIdx.x; e < base + EC; e += blockDim.x) {
        int dst = ei[NE + e];
        unsigned bin = (unsigned)(dst - lo);
        if (bin < BINS) {
            int src = ei[e];
            float w = dis[src] * ea[e] * dis[dst];
            int pos = pcb[dst] + atomicAdd(&cur[bin], 1);
            csr[pos] = make_int2(src, __float_as_int(w));
        }
    }
}

// Y[n,HID] = X[n,K] @ W[K,HID].  W staged in LDS. 1 wave per row, lane = col.
template <int K>
__global__ void gemm_kernel(const float* __restrict__ X,
                            const float* __restrict__ W,
                            float* __restrict__ Y) {
    __shared__ float w_lds[K * HID];
    for (int idx = threadIdx.x; idx < K * HID; idx += blockDim.x)
        w_lds[idx] = W[idx];
    __syncthreads();
    int wave = threadIdx.x >> 6;
    int lane = threadIdx.x & 63;
    int row = blockIdx.x * 4 + wave;
    if (row >= NN) return;
    const float4* x4 = (const float4*)(X + (size_t)row * K);
    float acc = 0.0f;
#pragma unroll
    for (int k4 = 0; k4 < K / 4; ++k4) {
        float4 xv = x4[k4];
        acc += xv.x * w_lds[(k4 * 4 + 0) * HID + lane];
        acc += xv.y * w_lds[(k4 * 4 + 1) * HID + lane];
        acc += xv.z * w_lds[(k4 * 4 + 2) * HID + lane];
        acc += xv.w * w_lds[(k4 * 4 + 3) * HID + lane];
    }
    Y[(size_t)row * HID + lane] = acc;
}

// OUT[node] = act( sum_e w*HW[src] + dis^2*HW[node] + bias )   (1 wave/node)
template <bool RELU>
__global__ void gather_kernel(const int2* __restrict__ csr,
                              const int* __restrict__ offs,
                              const int* __restrict__ indeg,
                              const float* __restrict__ dis,
                              const float* __restrict__ HW,
                              const float* __restrict__ bias,
                              float* __restrict__ OUT) {
    int node = blockIdx.x * 4 + (threadIdx.x >> 6);
    int lane = threadIdx.x & 63;
    if (node >= NN) return;
    int start = offs[node];
    int n = indeg[node];
    float d = dis[node];
    float a0 = d * d * HW[(size_t)node * HID + lane];
    float a1 = 0.f, a2 = 0.f, a3 = 0.f;
    int j = 0;
    for (; j + 4 <= n; j += 4) {
        int2 r0 = csr[start + j + 0];
        int2 r1 = csr[start + j + 1];
        int2 r2 = csr[start + j + 2];
        int2 r3 = csr[start + j + 3];
        a0 += __int_as_float(r0.y) * HW[(size_t)r0.x * HID + lane];
        a1 += __int_as_float(r1.y) * HW[(size_t)r1.x * HID + lane];
        a2 += __int_as_float(r2.y) * HW[(size_t)r2.x * HID + lane];
        a3 += __int_as_float(r3.y) * HW[(size_t)r3.x * HID + lane];
    }
    for (; j < n; ++j) {
        int2 r = csr[start + j];
        a0 += __int_as_float(r.y) * HW[(size_t)r.x * HID + lane];
    }
    float v = (a0 + a1) + (a2 + a3) + bias[lane];
    OUT[(size_t)node * HID + lane] = RELU ? fmaxf(v, 0.0f) : v;
}

// gstart[g] = lower_bound(batch, g)   (batch is sorted); gstart[NG] = NN
__global__ void gbounds_kernel(const int* __restrict__ batch, int* __restrict__ gstart) {
    int g = blockIdx.x * blockDim.x + threadIdx.x;
    if (g > NG) return;
    int lo = 0, hi = NN;
    while (lo < hi) {
        int mid = (lo + hi) >> 1;
        if (batch[mid] < g) lo = mid + 1; else hi = mid;
    }
    gstart[g] = lo;
}

// out[g] = (mean of H rows in [gstart[g],gstart[g+1])) . Wlin + blin
__global__ void pool_head_kernel(const float* __restrict__ H,
                                 const int* __restrict__ gstart,
                                 const float* __restrict__ Wlin,
                                 const float* __restrict__ blin,
                                 float* __restrict__ out) {
    int g = blockIdx.x;
    int lane = threadIdx.x;
    int s = gstart[g], e = gstart[g + 1];
    float a0 = 0.f, a1 = 0.f, a2 = 0.f, a3 = 0.f;
    int i = s;
    for (; i + 4 <= e; i += 4) {
        a0 += H[(size_t)(i + 0) * HID + lane];
        a1 += H[(size_t)(i + 1) * HID + lane];
        a2 += H[(size_t)(i + 2) * HID + lane];
        a3 += H[(size_t)(i + 3) * HID + lane];
    }
    for (; i < e; ++i) a0 += H[(size_t)i * HID + lane];
    float mean = ((a0 + a1) + (a2 + a3)) / fmaxf((float)(e - s), 1.0f);
    float v = mean * Wlin[lane];
    for (int off = 32; off > 0; off >>= 1) v += __shfl_down(v, off, 64);
    if (lane == 0) out[g] = v + blin[0];
}

extern "C" void kernel_launch(void* const* d_in, const int* in_sizes, int n_in,
                              void* d_out, int out_size, void* d_ws, size_t ws_size,
                              hipStream_t stream) {
    const float* x     = (const float*)d_in[0];
    const int*   ei    = (const int*)d_in[1];
    const float* ea    = (const float*)d_in[2];
    const int*   batch = (const int*)d_in[3];
    const float* W1    = (const float*)d_in[4];
    const float* b1    = (const float*)d_in[5];
    const float* W2    = (const float*)d_in[6];
    const float* b2    = (const float*)d_in[7];
    const float* Wlin  = (const float*)d_in[8];
    const float* blin  = (const float*)d_in[9];
    float*       out   = (float*)d_out;

    char* ws = (char*)d_ws;
    auto alloc = [&](size_t bytes) {
        void* p = (void*)ws;
        ws += (bytes + 255) / 256 * 256;
        return p;
    };
    float* dis    = (float*)alloc((size_t)NN * 4);
    int*   indeg  = (int*)alloc((size_t)NN * 4);
    int*   offs   = (int*)alloc((size_t)NN * 4);
    int*   csum   = (int*)alloc((size_t)NCH * 4);
    int*   coff   = (int*)alloc((size_t)NCH * 4);
    int*   gstart = (int*)alloc((size_t)(NG + 1) * 4);
    int2*  csr    = (int2*)alloc((size_t)NE * 8);
    float* A      = (float*)alloc((size_t)NN * HID * 4);   // hw1/hw2; aliases pc+ps
    float* B      = (float*)alloc((size_t)NN * HID * 4);   // h1 then h2
    int*   pc     = (int*)A;                                // [CC][NN] counts -> chunkoffs
    float* ps     = (float*)(A + (size_t)CC * NN);          // [CC][NN] weighted sums

    // histogram -> indeg, dis   (no global atomics anywhere)
    hist_kernel<<<RR * CC, 256, 0, stream>>>(ei, ea, pc, ps);
    reduce_kernel<<<(NN + 255) / 256, 256, 0, stream>>>(pc, ps, indeg, dis);

    // offs = exclusive_scan(indeg); pc -> per-chunk base offsets
    chunksum_kernel<<<NCH, 256, 0, stream>>>(indeg, csum);
    scanchunks_kernel<<<1, 128, 0, stream>>>(csum, coff);
    chunkscan_kernel<<<NCH, CHUNK, 0, stream>>>(indeg, coff, offs);
    chunkoff_kernel<<<(NN + 255) / 256, 256, 0, stream>>>(pc, offs);
    fill_kernel<<<RR * CC, 256, 0, stream>>>(ei, ea, dis, pc, csr);

    // conv1: h1 = relu(gather(x@W1) + self + b1)    (gemm1 overwrites pc/ps)
    gemm_kernel<IN_DIM><<<(NN + 3) / 4, 256, 0, stream>>>(x, W1, A);
    gather_kernel<true><<<(NN + 3) / 4, 256, 0, stream>>>(csr, offs, indeg, dis, A, b1, B);

    // conv2: h2 = gather(h1@W2) + self + b2
    gemm_kernel<HID><<<(NN + 3) / 4, 256, 0, stream>>>(B, W2, A);
    gather_kernel<false><<<(NN + 3) / 4, 256, 0, stream>>>(csr, offs, indeg, dis, A, b2, B);

    // mean-pool per sorted-contiguous graph range + head
    gbounds_kernel<<<(NG + 256) / 256, 256, 0, stream>>>(batch, gstart);
    pool_head_kernel<<<NG, 64, 0, stream>>>(B, gstart, Wlin, blin, out);
}